// Round 12
// baseline (317.367 us; speedup 1.0000x reference)
//
#include <hip/hip_runtime.h>
#include <hip/hip_bf16.h>

typedef __bf16 bf16_t;
typedef __bf16 bf16x8 __attribute__((ext_vector_type(8)));
typedef __bf16 bf16x4 __attribute__((ext_vector_type(4)));
typedef float f32x4 __attribute__((ext_vector_type(4)));
typedef float f32x16 __attribute__((ext_vector_type(16)));

#define LOG2E 1.4426950408889634f

// ---------------------------------------------------------------------------
// async global->LDS, 16B per lane (dest must be wave-uniform base + lane*16)
__device__ __forceinline__ void gload_lds16(const void* g, void* l) {
  __builtin_amdgcn_global_load_lds((const __attribute__((address_space(1))) void*)g,
                                   (__attribute__((address_space(3))) void*)l, 16, 0, 0);
}

// pack two f32 -> one u32 holding 2 bf16 (lo = a, hi = b)
__device__ __forceinline__ unsigned pk_bf16(float a, float b) {
  unsigned r;
  asm("v_cvt_pk_bf16_f32 %0, %1, %2" : "=v"(r) : "v"(a), "v"(b));
  return r;
}

// ---------------------------------------------------------------------------
// Fused prep kernel (Wot handled by proj helper blocks): 256-thread blocks.
__device__ __forceinline__ void trcvt_body(const float* src, bf16_t* dst, int R,
                                           int C, int cx, int cy, int tx, int ty,
                                           float (*tile)[33], bool perm) {
  int c0 = cx * 32, r0 = cy * 32;
#pragma unroll
  for (int i = 0; i < 4; ++i)
    tile[ty + i * 8][tx] = src[(size_t)(r0 + ty + i * 8) * C + c0 + tx];
  __syncthreads();
#pragma unroll
  for (int i = 0; i < 4; ++i) {
    int rc = c0 + ty + i * 8;
    int r_out = rc;
    if (perm) {
      int dd = rc & 127;
      int q = (dd & 15) + (dd & 16) + (((dd >> 5) & 1) ? 64 : 0) + ((dd >> 6) ? 32 : 0);
      r_out = (rc & ~127) | q;
    }
    dst[(size_t)r_out * R + r0 + tx] = (bf16_t)tile[tx][ty + i * 8];
  }
}

__global__ __launch_bounds__(256) void prep_kernel(
    const float* __restrict__ hidden, const float* __restrict__ Wq,
    const float* __restrict__ Wk, const float* __restrict__ Wv,
    bf16_t* __restrict__ hB, bf16_t* __restrict__ Wqt,
    bf16_t* __restrict__ Wkvt, float* __restrict__ cosT,
    float* __restrict__ sinT) {
  __shared__ float tile[32][33];
  const int bx = blockIdx.x;
  const int t = threadIdx.x;
  const int tx = t & 31, ty = t >> 5;
  if (bx < 4096) {
    int i = bx * 256 + t;
    const float4* s4 = (const float4*)hidden;
    float4 a = s4[2 * i], b = s4[2 * i + 1];
    bf16x8 o;
    o[0] = (bf16_t)a.x; o[1] = (bf16_t)a.y; o[2] = (bf16_t)a.z; o[3] = (bf16_t)a.w;
    o[4] = (bf16_t)b.x; o[5] = (bf16_t)b.y; o[6] = (bf16_t)b.z; o[7] = (bf16_t)b.w;
    *(bf16x8*)(hB + 8 * (size_t)i) = o;
  } else if (bx < 4608) {
    int i = (bx - 4096) * 256 + t;  // 2048*64
    int s = i >> 6, d = i & 63;
    float ang = (float)s * powf(10000.0f, -(float)d * (1.0f / 64.0f));
    cosT[i] = cosf(ang);
    sinT[i] = sinf(ang);
  } else if (bx < 20992) {
    int j = bx - 4608;
    trcvt_body(Wq, Wqt, 4096, 4096, j % 128, j / 128, tx, ty, tile, true);
  } else if (bx < 25088) {
    int j = bx - 20992;
    trcvt_body(Wk, Wkvt, 4096, 1024, j % 32, j / 32, tx, ty, tile, true);
  } else {
    int j = bx - 25088;
    trcvt_body(Wv, Wkvt + (size_t)1024 * 4096, 4096, 1024, j % 32, j / 32, tx, ty, tile, false);
  }
}

// bf16 [R][C] -> bf16 [C][R]  (V -> V^T for the attn PV A-operand)
__global__ __launch_bounds__(256) void trb_kernel(const bf16_t* __restrict__ src,
                                                  bf16_t* __restrict__ dst, int R, int C) {
  __shared__ bf16_t tile[32][33];
  int c0 = blockIdx.x * 32, r0 = blockIdx.y * 32;
  int tx = threadIdx.x, ty = threadIdx.y;
#pragma unroll
  for (int i = 0; i < 4; ++i)
    tile[ty + i * 8][tx] = src[(size_t)(r0 + ty + i * 8) * C + c0 + tx];
  __syncthreads();
#pragma unroll
  for (int i = 0; i < 4; ++i)
    dst[(size_t)(c0 + ty + i * 8) * R + r0 + tx] = tile[tx][ty + i * 8];
}

// ---------------------------------------------------------------------------
// Projection GEMM v3: 256x256 tile, 8 waves, BK=64, TWO fat phases/K-tile
// (4 barriers/tile instead of 8; 32 MFMA per phase). Staging: ph0 stages
// A(j+1)->cn (A(cn) dead since tile j-1 ph1), ph1 stages B(j+2)->c (B(c)
// dead after ph0). Tile-end vmcnt(4) leaves only B(j+2) in flight.
// Blocks 192..255: Wot transpose helpers (idle CUs; ~12us, hidden).
__global__ __launch_bounds__(512, 2) void proj_gemm_kernel(
    const bf16_t* __restrict__ A, const bf16_t* __restrict__ Wqt,
    const bf16_t* __restrict__ Wkvt, const float* __restrict__ cosT,
    const float* __restrict__ sinT, bf16_t* __restrict__ Qb,
    bf16_t* __restrict__ Kb, bf16_t* __restrict__ Vb,
    const float* __restrict__ Wo, bf16_t* __restrict__ Wot) {
  constexpr int K = 4096;
  extern __shared__ unsigned char sMem[];
  const int bx = blockIdx.x;
  const int t = threadIdx.x;  // 0..511

  if (bx >= 192) {
    // ---- Wot helper: transpose+cvt a 64-column stripe of Wo (4096x4096 f32)
    float(*tl)[65] = (float(*)[65])sMem;
    const int c0 = (bx - 192) * 64;
    const int tc = t & 63, tr = t >> 6;  // 64 x 8
    for (int r0 = 0; r0 < 4096; r0 += 64) {
#pragma unroll
      for (int i = 0; i < 8; ++i)
        tl[tr + 8 * i][tc] = Wo[(size_t)(r0 + tr + 8 * i) * 4096 + c0 + tc];
      __syncthreads();
#pragma unroll
      for (int i = 0; i < 8; ++i)
        Wot[(size_t)(c0 + tr + 8 * i) * 4096 + r0 + tc] = (bf16_t)tl[tc][tr + 8 * i];
      __syncthreads();
    }
    return;
  }

  const int mt = bx & 7, nt = bx >> 3;  // 8 x 24
  const int bm = mt * 256;
  const bf16_t* Btb = (nt < 16) ? (Wqt + (size_t)nt * 256 * K)
                                : (Wkvt + (size_t)(nt - 16) * 256 * K);

  const int rowU = t >> 2;
  const int cole = ((t & 3) * 8) ^ ((rowU & 8) ? 16 : 0);
  const bf16_t* aS = A + (size_t)(bm + rowU) * K + cole;
  const bf16_t* bS = Btb + (size_t)rowU * K + cole;

  const int lane = t & 63, w = t >> 6;
  const int wm = w >> 2, wn = w & 3;
  const int lr = lane & 15, lq = lane >> 4;
  const int colb = (lq * 16) ^ ((lr & 8) ? 32 : 0);

  auto stA = [&](int c, int h, int j) {
    unsigned char* d = sMem + c * 65536 + h * 16384 + t * 16;
    const bf16_t* g = aS + (size_t)h * 128 * K + j * 64;
    gload_lds16(g, d);
    gload_lds16(g + 32, d + 8192);
  };
  auto stB = [&](int c, int h, int j) {
    unsigned char* d = sMem + c * 65536 + 32768 + h * 16384 + t * 16;
    const bf16_t* g = bS + (size_t)h * 128 * K + j * 64;
    gload_lds16(g, d);
    gload_lds16(g + 32, d + 8192);
  };
  auto LA = [&](int c, int half, int mi, int kk) {
    return *(const bf16x8*)(sMem + c * 65536 + wm * 16384 + kk * 8192 +
                            (half * 64 + mi * 16 + lr) * 64 + colb);
  };
  auto LB = [&](int c, int ni, int kk) {
    return *(const bf16x8*)(sMem + c * 65536 + 32768 + (wn >> 1) * 16384 + kk * 8192 +
                            ((wn & 1) * 64 + ni * 16 + lr) * 64 + colb);
  };

  f32x4 acc[8][4];
#pragma unroll
  for (int i = 0; i < 8; ++i)
#pragma unroll
    for (int n = 0; n < 4; ++n) acc[i][n] = f32x4{0.f, 0.f, 0.f, 0.f};

  // prologue: A(0), B(0), B(1); wait all but B(1)
  stA(0, 0, 0); stA(0, 1, 0); stB(0, 0, 0); stB(0, 1, 0);
  stB(1, 0, 1); stB(1, 1, 1);
  asm volatile("s_waitcnt vmcnt(4)" ::: "memory");
  __builtin_amdgcn_s_barrier();
  __builtin_amdgcn_sched_barrier(0);

  bf16x8 af[4][2], bfr[4][2];
  for (int j = 0; j < 64; ++j) {
    const int c = j & 1, cn = c ^ 1;
    const int jp1 = (j + 1 < 64) ? j + 1 : 63;
    const int jp2 = (j + 2 < 64) ? j + 2 : 63;
    // ---- ph0: read A-half0 + ALL B frags; stage A0,A1(j+1)->cn; MFMA m0 x n0..3
#pragma unroll
    for (int mi = 0; mi < 4; ++mi)
#pragma unroll
      for (int kk = 0; kk < 2; ++kk) af[mi][kk] = LA(c, 0, mi, kk);
#pragma unroll
    for (int ni = 0; ni < 4; ++ni)
#pragma unroll
      for (int kk = 0; kk < 2; ++kk) bfr[ni][kk] = LB(c, ni, kk);
    stA(cn, 0, jp1);
    stA(cn, 1, jp1);
    __builtin_amdgcn_s_barrier();
    __builtin_amdgcn_sched_barrier(0);
    __builtin_amdgcn_s_setprio(1);
#pragma unroll
    for (int kk = 0; kk < 2; ++kk)
#pragma unroll
      for (int mi = 0; mi < 4; ++mi)
#pragma unroll
        for (int ni = 0; ni < 4; ++ni)
          acc[mi][ni] = __builtin_amdgcn_mfma_f32_16x16x32_bf16(af[mi][kk], bfr[ni][kk],
                                                                acc[mi][ni], 0, 0, 0);
    __builtin_amdgcn_s_setprio(0);
    __builtin_amdgcn_sched_barrier(0);
    __builtin_amdgcn_s_barrier();
    // ---- ph1: read A-half1 (B reused from regs); stage B0,B1(j+2)->c;
    //      MFMA m1 x n0..3; tile-end vmcnt(4) (only B(j+2) left in flight)
#pragma unroll
    for (int mi = 0; mi < 4; ++mi)
#pragma unroll
      for (int kk = 0; kk < 2; ++kk) af[mi][kk] = LA(c, 1, mi, kk);
    stB(c, 0, jp2);
    stB(c, 1, jp2);
    __builtin_amdgcn_s_barrier();
    __builtin_amdgcn_sched_barrier(0);
    __builtin_amdgcn_s_setprio(1);
#pragma unroll
    for (int kk = 0; kk < 2; ++kk)
#pragma unroll
      for (int mi = 0; mi < 4; ++mi)
#pragma unroll
        for (int ni = 0; ni < 4; ++ni)
          acc[4 + mi][ni] = __builtin_amdgcn_mfma_f32_16x16x32_bf16(
              af[mi][kk], bfr[ni][kk], acc[4 + mi][ni], 0, 0, 0);
    __builtin_amdgcn_s_setprio(0);
    asm volatile("s_waitcnt vmcnt(4)" ::: "memory");
    __builtin_amdgcn_sched_barrier(0);
    __builtin_amdgcn_s_barrier();
  }

  if (nt < 20) {
    const bool isQ = nt < 16;
    bf16_t* dst = isQ ? Qb : Kb;
    const int ld = isQ ? 4096 : 1024;
    const int hh = isQ ? (nt * 2 + (wn >> 1)) : ((nt - 16) * 2 + (wn >> 1));
    // Q: 1/sqrt(128) * log2(e) folded (softmax uses exp2); K: unscaled
    const float qs = isQ ? 0.12751743f : 1.0f;
    const int dbase = lr + 32 * (wn & 1);
#pragma unroll
    for (int half = 0; half < 2; ++half)
#pragma unroll
      for (int mi = 0; mi < 4; ++mi)
#pragma unroll
        for (int ni = 0; ni < 2; ++ni) {
          int d = dbase + 16 * ni;
#pragma unroll
          for (int r = 0; r < 4; ++r) {
            int srow = bm + wm * 128 + half * 64 + mi * 16 + lq * 4 + r;
            float cv = cosT[srow * 64 + d], sv = sinT[srow * 64 + d];
            float x1 = acc[half * 4 + mi][ni][r], x2 = acc[half * 4 + mi][ni + 2][r];
            dst[(size_t)srow * ld + hh * 128 + d] = (bf16_t)((x1 * cv - x2 * sv) * qs);
            dst[(size_t)srow * ld + hh * 128 + d + 64] = (bf16_t)((x2 * cv + x1 * sv) * qs);
          }
        }
  } else {
    const int col0 = (nt - 20) * 256 + wn * 64;
#pragma unroll
    for (int half = 0; half < 2; ++half)
#pragma unroll
      for (int mi = 0; mi < 4; ++mi)
#pragma unroll
        for (int ni = 0; ni < 4; ++ni)
#pragma unroll
          for (int r = 0; r < 4; ++r) {
            int srow = bm + wm * 128 + half * 64 + mi * 16 + lq * 4 + r;
            Vb[(size_t)srow * 1024 + col0 + ni * 16 + lr] =
                (bf16_t)acc[half * 4 + mi][ni][r];
          }
  }
}

// ---------------------------------------------------------------------------
// Out-projection GEMM v3: 256x128 tile, 8 waves (2Mx4N, per-wave 128x32),
// TWO fat phases/K-tile (4 barriers; 16 MFMA per phase), grid 256 blocks.
__global__ __launch_bounds__(512, 2) void out_gemm_kernel(
    const bf16_t* __restrict__ A, const bf16_t* __restrict__ B0,
    float* __restrict__ Cout) {
  constexpr int K = 4096;
  extern __shared__ unsigned char sMem[];
  const int bx = blockIdx.x;
  const int mt = bx & 7, nt = bx >> 3;  // 8 x 32
  const int bm = mt * 256;
  const bf16_t* Bt = B0 + (size_t)nt * 128 * K;

  const int t = threadIdx.x;  // 0..511
  const int rowU = t >> 2;
  const int cole = ((t & 3) * 8) ^ ((rowU & 8) ? 16 : 0);
  const bf16_t* aS = A + (size_t)(bm + rowU) * K + cole;
  const bf16_t* bS = Bt + (size_t)rowU * K + cole;

  const int lane = t & 63, w = t >> 6;
  const int wm = w >> 2, wn = w & 3;
  const int lr = lane & 15, lq = lane >> 4;
  const int colb = (lq * 16) ^ ((lr & 8) ? 32 : 0);

  auto stA = [&](int c, int h, int j) {
    unsigned char* d = sMem + c * 49152 + h * 16384 + t * 16;
    const bf16_t* g = aS + (size_t)h * 128 * K + j * 64;
    gload_lds16(g, d);
    gload_lds16(g + 32, d + 8192);
  };
  auto stB = [&](int c, int j) {
    unsigned char* d = sMem + c * 49152 + 32768 + t * 16;
    const bf16_t* g = bS + j * 64;
    gload_lds16(g, d);
    gload_lds16(g + 32, d + 8192);
  };
  auto LA = [&](int c, int half, int mi, int kk) {
    return *(const bf16x8*)(sMem + c * 49152 + wm * 16384 + kk * 8192 +
                            (half * 64 + mi * 16 + lr) * 64 + colb);
  };
  auto LB = [&](int c, int ni, int kk) {
    return *(const bf16x8*)(sMem + c * 49152 + 32768 + kk * 8192 +
                            (wn * 32 + ni * 16 + lr) * 64 + colb);
  };

  f32x4 acc[8][2];
#pragma unroll
  for (int i = 0; i < 8; ++i)
#pragma unroll
    for (int n = 0; n < 2; ++n) acc[i][n] = f32x4{0.f, 0.f, 0.f, 0.f};

  // prologue: A(0), B(0), B(1); wait all but B(1)
  stA(0, 0, 0); stA(0, 1, 0); stB(0, 0);
  stB(1, 1);
  asm volatile("s_waitcnt vmcnt(2)" ::: "memory");
  __builtin_amdgcn_s_barrier();
  __builtin_amdgcn_sched_barrier(0);

  bf16x8 af[4][2], bfr[2][2];
  for (int j = 0; j < 64; ++j) {
    const int c = j & 1, cn = c ^ 1;
    const int jp1 = (j + 1 < 64) ? j + 1 : 63;
    const int jp2 = (j + 2 < 64) ? j + 2 : 63;
    // ---- ph0: read A-half0 + B n0/1; stage A0,A1(j+1)->cn; MFMA m0 x n0/1
#pragma unroll
    for (int mi = 0; mi < 4; ++mi)
#pragma unroll
      for (int kk = 0; kk < 2; ++kk) af[mi][kk] = LA(c, 0, mi, kk);
#pragma unroll
    for (int ni = 0; ni < 2; ++ni)
#pragma unroll
      for (int kk = 0; kk < 2; ++kk) bfr[ni][kk] = LB(c, ni, kk);
    stA(cn, 0, jp1);
    stA(cn, 1, jp1);
    __builtin_amdgcn_s_barrier();
    __builtin_amdgcn_sched_barrier(0);
    __builtin_amdgcn_s_setprio(1);
#pragma unroll
    for (int kk = 0; kk < 2; ++kk)
#pragma unroll
      for (int mi = 0; mi < 4; ++mi)
#pragma unroll
        for (int ni = 0; ni < 2; ++ni)
          acc[mi][ni] = __builtin_amdgcn_mfma_f32_16x16x32_bf16(af[mi][kk], bfr[ni][kk],
                                                                acc[mi][ni], 0, 0, 0);
    __builtin_amdgcn_s_setprio(0);
    __builtin_amdgcn_sched_barrier(0);
    __builtin_amdgcn_s_barrier();
    // ---- ph1: read A-half1 (B reused); stage B(j+2)->c; MFMA m1 x n0/1;
    //      tile-end vmcnt(2) (only B(j+2) left in flight)
#pragma unroll
    for (int mi = 0; mi < 4; ++mi)
#pragma unroll
      for (int kk = 0; kk < 2; ++kk) af[mi][kk] = LA(c, 1, mi, kk);
    stB(c, jp2);
    __builtin_amdgcn_s_barrier();
    __builtin_amdgcn_sched_barrier(0);
    __builtin_amdgcn_s_setprio(1);
#pragma unroll
    for (int kk = 0; kk < 2; ++kk)
#pragma unroll
      for (int mi = 0; mi < 4; ++mi)
#pragma unroll
        for (int ni = 0; ni < 2; ++ni)
          acc[4 + mi][ni] = __builtin_amdgcn_mfma_f32_16x16x32_bf16(
              af[mi][kk], bfr[ni][kk], acc[4 + mi][ni], 0, 0, 0);
    __builtin_amdgcn_s_setprio(0);
    asm volatile("s_waitcnt vmcnt(2)" ::: "memory");
    __builtin_amdgcn_sched_barrier(0);
    __builtin_amdgcn_s_barrier();
  }

  // epilogue: row = bm + wm*128 + half*64 + mi*16 + lq*4 + r,
  //           col = nt*128 + wn*32 + ni*16 + lr
#pragma unroll
  for (int half = 0; half < 2; ++half)
#pragma unroll
    for (int mi = 0; mi < 4; ++mi)
#pragma unroll
      for (int ni = 0; ni < 2; ++ni)
#pragma unroll
        for (int r = 0; r < 4; ++r) {
          int row = bm + wm * 128 + half * 64 + mi * 16 + lq * 4 + r;
          Cout[(size_t)row * 4096 + nt * 128 + wn * 32 + ni * 16 + lr] =
              acc[half * 4 + mi][ni][r];
        }
}

// ---------------------------------------------------------------------------
// Flash attention v5: 8 waves x 32 q-rows, swapped-operand 32x32x16 MFMA,
// exp2-domain softmax, P in registers, mask in LDS, counted vmcnt(4) loop.
__global__ __launch_bounds__(512) void attn_kernel(
    const bf16_t* __restrict__ Qb, const bf16_t* __restrict__ Kb,
    const bf16_t* __restrict__ Vt, const float* __restrict__ mask,
    bf16_t* __restrict__ Ob) {
  extern __shared__ unsigned char sMem[];
  const int bx = blockIdx.x;
  const int h = bx >> 3, qt = bx & 7;
  const int kvh = h >> 2;
  const int t = threadIdx.x, lane = t & 63, w = t >> 6;
  const int ln = lane & 31, hi = lane >> 5;
  const int q0 = qt * 256 + w * 32;
  const int swz = (ln & 7) << 4;

  bf16x8 qf[8];
#pragma unroll
  for (int ds = 0; ds < 8; ++ds)
    qf[ds] = *(const bf16x8*)(Qb + (size_t)(q0 + ln) * 4096 + h * 128 + ds * 16 + hi * 8);

  const int krow = t >> 4, kg = t & 15;
  const bf16_t* kSrc = Kb + (size_t)krow * 1024 + kvh * 128 +
                       (((kg * 16) ^ ((krow & 7) << 4)) >> 1);
  const int vrow = t >> 3, vg = t & 7;
  const bf16_t* vSrc = Vt + (size_t)(kvh * 128 + vrow) * 2048 +
                       (((vg * 16) ^ ((vrow & 7) << 4)) >> 1);

  auto stage = [&](int c, int kt) {  // uniform 4 loads per thread
    unsigned char* kD = sMem + c * 16384 + t * 16;
    unsigned char* vD = sMem + 32768 + c * 16384 + t * 16;
    gload_lds16(kSrc + (size_t)kt * 64 * 1024, kD);
    gload_lds16(kSrc + (size_t)(kt * 64 + 32) * 1024, kD + 8192);
    gload_lds16(vSrc + kt * 64, vD);
    gload_lds16(vSrc + (size_t)64 * 2048 + kt * 64, vD + 8192);
  };

  f32x16 o[4];
#pragma unroll
  for (int db = 0; db < 4; ++db)
#pragma unroll
    for (int e = 0; e < 16; ++e) o[db][e] = 0.f;
  float mrun = -1e30f, lp = 0.f;

  stage(0, 0);
  gload_lds16(mask + t * 4, sMem + 65536 + t * 16);
  asm volatile("s_waitcnt vmcnt(0)" ::: "memory");
  __builtin_amdgcn_s_barrier();
  __builtin_amdgcn_sched_barrier(0);

  for (int kt = 0; kt < 32; ++kt) {
    const int c = kt & 1;
    if (kt < 31) {
      stage(c ^ 1, kt + 1);
      asm volatile("s_waitcnt vmcnt(4)" ::: "memory");
    } else {
      asm volatile("s_waitcnt vmcnt(0)" ::: "memory");
    }
    __builtin_amdgcn_s_barrier();
    __builtin_amdgcn_sched_barrier(0);

    const unsigned char* sK = sMem + c * 16384;
    const unsigned char* sV = sMem + 32768 + c * 16384;
    const unsigned char* sMk = sMem + 65536 + kt * 256;

#pragma unroll
    for (int sub = 0; sub < 2; ++sub) {
      f32x16 s;
#pragma unroll
      for (int e = 0; e < 16; ++e) s[e] = 0.f;
      __builtin_amdgcn_s_setprio(1);
#pragma unroll
      for (int ds = 0; ds < 8; ++ds) {
        bf16x8 kf = *(const bf16x8*)(sK + (sub * 32 + ln) * 256 +
                                     ((ds * 32 + hi * 16) ^ swz));
        s = __builtin_amdgcn_mfma_f32_32x32x16_bf16(kf, qf[ds], s, 0, 0, 0);
      }
      __builtin_amdgcn_s_setprio(0);
#pragma unroll
      for (int rg = 0; rg < 4; ++rg) {
        float4 mv = *(const float4*)(sMk + (sub * 32 + rg * 8 + 4 * hi) * 4);
        s[rg * 4 + 0] += LOG2E * mv.x; s[rg * 4 + 1] += LOG2E * mv.y;
        s[rg * 4 + 2] += LOG2E * mv.z; s[rg * 4 + 3] += LOG2E * mv.w;
      }
      float pm = s[0];
#pragma unroll
      for (int e = 1; e < 16; ++e) pm = fmaxf(pm, s[e]);
      pm = fmaxf(pm, __shfl_xor(pm, 32));
      if (!__all(pm - mrun <= 11.5f)) {
        float nm = fmaxf(mrun, pm);
        float al = exp2f(mrun - nm);
        mrun = nm;
        lp *= al;
#pragma unroll
        for (int db = 0; db < 4; ++db)
#pragma unroll
          for (int e = 0; e < 16; ++e) o[db][e] *= al;
      }
      float p[16], ps = 0.f;
#pragma unroll
      for (int e = 0; e < 16; ++e) {
        p[e] = exp2f(s[e] - mrun);
        ps += p[e];
      }
      lp += ps;
#pragma unroll
      for (int hh = 0; hh < 2; ++hh) {
        unsigned w0 = pk_bf16(p[8 * hh + 0], p[8 * hh + 1]);
        unsigned w1 = pk_bf16(p[8 * hh + 2], p[8 * hh + 3]);
        unsigned w2 = pk_bf16(p[8 * hh + 4], p[8 * hh + 5]);
        unsigned w3 = pk_bf16(p[8 * hh + 6], p[8 * hh + 7]);
        unsigned pw0 = __shfl_xor((int)w0, 32), pw1 = __shfl_xor((int)w1, 32);
        unsigned pw2 = __shfl_xor((int)w2, 32), pw3 = __shfl_xor((int)w3, 32);
        union { unsigned u[4]; bf16x8 v; } pf;
        pf.u[0] = hi ? pw2 : w0;
        pf.u[1] = hi ? pw3 : w1;
        pf.u[2] = hi ? w2 : pw0;
        pf.u[3] = hi ? w3 : pw1;
        __builtin_amdgcn_s_setprio(1);
#pragma unroll
        for (int db = 0; db < 4; ++db) {
          bf16x8 vf = *(const bf16x8*)(sV + (db * 32 + ln) * 128 +
                                       ((sub * 64 + hh * 32 + hi * 16) ^ swz));
          o[db] = __builtin_amdgcn_mfma_f32_32x32x16_bf16(vf, pf.v, o[db], 0, 0, 0);
        }
        __builtin_amdgcn_s_setprio(0);
      }
    }
    __builtin_amdgcn_s_barrier();
    __builtin_amdgcn_sched_barrier(0);
  }

  float l = lp + __shfl_xor(lp, 32);
  float inv = 1.0f / l;
  bf16_t* orow = Ob + (size_t)(q0 + ln) * 4096 + h * 128;
#pragma unroll
  for (int db = 0; db < 4; ++db)
#pragma unroll
    for (int rg = 0; rg < 4; ++rg) {
      bf16x4 ov;
#pragma unroll
      for (int j = 0; j < 4; ++j) ov[j] = (bf16_t)(o[db][rg * 4 + j] * inv);
      *(bf16x4*)(orow + db * 32 + rg * 8 + hi * 4) = ov;
    }
}

// ---------------------------------------------------------------------------
extern "C" void kernel_launch(void* const* d_in, const int* in_sizes, int n_in,
                              void* d_out, int out_size, void* d_ws, size_t ws_size,
                              hipStream_t stream) {
  const float* hidden = (const float*)d_in[0];
  const float* mask = (const float*)d_in[1];
  const float* Wq = (const float*)d_in[2];
  const float* Wk = (const float*)d_in[3];
  const float* Wv = (const float*)d_in[4];
  const float* Wo = (const float*)d_in[5];
  float* out = (float*)d_out;
  char* ws = (char*)d_ws;

  bf16_t* hB   = (bf16_t*)(ws + 0);          //  16 MB  hidden bf16 [2048][4096]
  bf16_t* Wqt  = (bf16_t*)(ws + 16777216);   //  32 MB  Wq^T perm [4096][4096]
  bf16_t* Wkvt = (bf16_t*)(ws + 50331648);   //  16 MB  Wk^T perm | Wv^T [2048][4096]
  bf16_t* Wot  = (bf16_t*)(ws + 67108864);   //  32 MB  Wo^T  [4096][4096]
  bf16_t* Qb   = (bf16_t*)(ws + 100663296);  //  16 MB  Q roped+scaled [2048][4096]
  bf16_t* Kb   = (bf16_t*)(ws + 117440512);  //   4 MB  K roped [2048][1024]
  bf16_t* Vb   = (bf16_t*)(ws + 121634816);  //   4 MB  V [2048][1024]
  bf16_t* Vt   = (bf16_t*)(ws + 125829120);  //   4 MB  V^T [1024][2048]
  bf16_t* Ob   = (bf16_t*)(ws + 130023424);  //  16 MB  attn out [2048][4096]
  float*  cosT = (float*)(ws + 146800640);   // 0.5 MB
  float*  sinT = (float*)(ws + 147324928);   // 0.5 MB

  hipFuncSetAttribute((const void*)attn_kernel,
                      hipFuncAttributeMaxDynamicSharedMemorySize, 73728);
  hipFuncSetAttribute((const void*)proj_gemm_kernel,
                      hipFuncAttributeMaxDynamicSharedMemorySize, 131072);
  hipFuncSetAttribute((const void*)out_gemm_kernel,
                      hipFuncAttributeMaxDynamicSharedMemorySize, 98304);

  prep_kernel<<<29184, 256, 0, stream>>>(hidden, Wq, Wk, Wv, hB, Wqt, Wkvt,
                                         cosT, sinT);
  proj_gemm_kernel<<<256, 512, 131072, stream>>>(hB, Wqt, Wkvt, cosT, sinT,
                                                 Qb, Kb, Vb, Wo, Wot);
  trb_kernel<<<dim3(32, 64), dim3(32, 8), 0, stream>>>(Vb, Vt, 2048, 1024);
  attn_kernel<<<256, 512, 73728, stream>>>(Qb, Kb, Vt, mask, Ob);
  out_gemm_kernel<<<256, 512, 98304, stream>>>(Ob, Wot, out);
}

// Round 13
// 310.627 us; speedup vs baseline: 1.0217x; 1.0217x over previous
//
#include <hip/hip_runtime.h>
#include <hip/hip_bf16.h>

typedef __bf16 bf16_t;
typedef __bf16 bf16x8 __attribute__((ext_vector_type(8)));
typedef __bf16 bf16x4 __attribute__((ext_vector_type(4)));
typedef float f32x4 __attribute__((ext_vector_type(4)));
typedef float f32x16 __attribute__((ext_vector_type(16)));

#define LOG2E 1.4426950408889634f

// ---------------------------------------------------------------------------
// async global->LDS, 16B per lane (dest must be wave-uniform base + lane*16)
__device__ __forceinline__ void gload_lds16(const void* g, void* l) {
  __builtin_amdgcn_global_load_lds((const __attribute__((address_space(1))) void*)g,
                                   (__attribute__((address_space(3))) void*)l, 16, 0, 0);
}

// pack two f32 -> one u32 holding 2 bf16 (lo = a, hi = b)
__device__ __forceinline__ unsigned pk_bf16(float a, float b) {
  unsigned r;
  asm("v_cvt_pk_bf16_f32 %0, %1, %2" : "=v"(r) : "v"(a), "v"(b));
  return r;
}

// ---------------------------------------------------------------------------
// Fused prep kernel (Wot handled by proj helper blocks): 256-thread blocks.
__device__ __forceinline__ void trcvt_body(const float* src, bf16_t* dst, int R,
                                           int C, int cx, int cy, int tx, int ty,
                                           float (*tile)[33], bool perm) {
  int c0 = cx * 32, r0 = cy * 32;
#pragma unroll
  for (int i = 0; i < 4; ++i)
    tile[ty + i * 8][tx] = src[(size_t)(r0 + ty + i * 8) * C + c0 + tx];
  __syncthreads();
#pragma unroll
  for (int i = 0; i < 4; ++i) {
    int rc = c0 + ty + i * 8;
    int r_out = rc;
    if (perm) {
      int dd = rc & 127;
      int q = (dd & 15) + (dd & 16) + (((dd >> 5) & 1) ? 64 : 0) + ((dd >> 6) ? 32 : 0);
      r_out = (rc & ~127) | q;
    }
    dst[(size_t)r_out * R + r0 + tx] = (bf16_t)tile[tx][ty + i * 8];
  }
}

__global__ __launch_bounds__(256) void prep_kernel(
    const float* __restrict__ hidden, const float* __restrict__ Wq,
    const float* __restrict__ Wk, const float* __restrict__ Wv,
    bf16_t* __restrict__ hB, bf16_t* __restrict__ Wqt,
    bf16_t* __restrict__ Wkvt, float* __restrict__ cosT,
    float* __restrict__ sinT) {
  __shared__ float tile[32][33];
  const int bx = blockIdx.x;
  const int t = threadIdx.x;
  const int tx = t & 31, ty = t >> 5;
  if (bx < 4096) {
    int i = bx * 256 + t;
    const float4* s4 = (const float4*)hidden;
    float4 a = s4[2 * i], b = s4[2 * i + 1];
    bf16x8 o;
    o[0] = (bf16_t)a.x; o[1] = (bf16_t)a.y; o[2] = (bf16_t)a.z; o[3] = (bf16_t)a.w;
    o[4] = (bf16_t)b.x; o[5] = (bf16_t)b.y; o[6] = (bf16_t)b.z; o[7] = (bf16_t)b.w;
    *(bf16x8*)(hB + 8 * (size_t)i) = o;
  } else if (bx < 4608) {
    int i = (bx - 4096) * 256 + t;  // 2048*64
    int s = i >> 6, d = i & 63;
    float ang = (float)s * powf(10000.0f, -(float)d * (1.0f / 64.0f));
    cosT[i] = cosf(ang);
    sinT[i] = sinf(ang);
  } else if (bx < 20992) {
    int j = bx - 4608;
    trcvt_body(Wq, Wqt, 4096, 4096, j % 128, j / 128, tx, ty, tile, true);
  } else if (bx < 25088) {
    int j = bx - 20992;
    trcvt_body(Wk, Wkvt, 4096, 1024, j % 32, j / 32, tx, ty, tile, true);
  } else {
    int j = bx - 25088;
    trcvt_body(Wv, Wkvt + (size_t)1024 * 4096, 4096, 1024, j % 32, j / 32, tx, ty, tile, false);
  }
}

// bf16 [R][C] -> bf16 [C][R]  (V -> V^T for the attn PV A-operand)
__global__ __launch_bounds__(256) void trb_kernel(const bf16_t* __restrict__ src,
                                                  bf16_t* __restrict__ dst, int R, int C) {
  __shared__ bf16_t tile[32][33];
  int c0 = blockIdx.x * 32, r0 = blockIdx.y * 32;
  int tx = threadIdx.x, ty = threadIdx.y;
#pragma unroll
  for (int i = 0; i < 4; ++i)
    tile[ty + i * 8][tx] = src[(size_t)(r0 + ty + i * 8) * C + c0 + tx];
  __syncthreads();
#pragma unroll
  for (int i = 0; i < 4; ++i)
    dst[(size_t)(c0 + ty + i * 8) * R + r0 + tx] = tile[tx][ty + i * 8];
}

// ---------------------------------------------------------------------------
// Projection GEMM (R6/R11 schedule — best measured): 256x256 tile, 8 waves,
// BK=64, 4 phases/K-tile, staging spread ph0..ph3, late vmcnt(4).
// NEW: XCD-chunked block swizzle (nwg=192, 192%8==0 -> bijective); each XCD
// owns a contiguous nt-range (3 B-panels, ~L2-resident).
// Blocks 192..255: Wot transpose helpers (idle CUs; ~12us, hidden).
__global__ __launch_bounds__(512, 2) void proj_gemm_kernel(
    const bf16_t* __restrict__ A, const bf16_t* __restrict__ Wqt,
    const bf16_t* __restrict__ Wkvt, const float* __restrict__ cosT,
    const float* __restrict__ sinT, bf16_t* __restrict__ Qb,
    bf16_t* __restrict__ Kb, bf16_t* __restrict__ Vb,
    const float* __restrict__ Wo, bf16_t* __restrict__ Wot) {
  constexpr int K = 4096;
  extern __shared__ unsigned char sMem[];
  const int bx = blockIdx.x;
  const int t = threadIdx.x;  // 0..511

  if (bx >= 192) {
    // ---- Wot helper: transpose+cvt a 64-column stripe of Wo (4096x4096 f32)
    float(*tl)[65] = (float(*)[65])sMem;
    const int c0 = (bx - 192) * 64;
    const int tc = t & 63, tr = t >> 6;  // 64 x 8
    for (int r0 = 0; r0 < 4096; r0 += 64) {
#pragma unroll
      for (int i = 0; i < 8; ++i)
        tl[tr + 8 * i][tc] = Wo[(size_t)(r0 + tr + 8 * i) * 4096 + c0 + tc];
      __syncthreads();
#pragma unroll
      for (int i = 0; i < 8; ++i)
        Wot[(size_t)(c0 + tr + 8 * i) * 4096 + r0 + tc] = (bf16_t)tl[tc][tr + 8 * i];
      __syncthreads();
    }
    return;
  }

  // XCD-chunked swizzle: XCD k (bx%8) gets logical tiles [k*24, (k+1)*24)
  const int swzb = (bx & 7) * 24 + (bx >> 3);
  const int mt = swzb & 7, nt = swzb >> 3;  // 8 x 24
  const int bm = mt * 256;
  const bf16_t* Btb = (nt < 16) ? (Wqt + (size_t)nt * 256 * K)
                                : (Wkvt + (size_t)(nt - 16) * 256 * K);

  const int rowU = t >> 2;
  const int cole = ((t & 3) * 8) ^ ((rowU & 8) ? 16 : 0);
  const bf16_t* aS = A + (size_t)(bm + rowU) * K + cole;
  const bf16_t* bS = Btb + (size_t)rowU * K + cole;

  const int lane = t & 63, w = t >> 6;
  const int wm = w >> 2, wn = w & 3;
  const int lr = lane & 15, lq = lane >> 4;
  const int colb = (lq * 16) ^ ((lr & 8) ? 32 : 0);

  auto stA = [&](int c, int h, int j) {
    unsigned char* d = sMem + c * 65536 + h * 16384 + t * 16;
    const bf16_t* g = aS + (size_t)h * 128 * K + j * 64;
    gload_lds16(g, d);
    gload_lds16(g + 32, d + 8192);
  };
  auto stB = [&](int c, int h, int j) {
    unsigned char* d = sMem + c * 65536 + 32768 + h * 16384 + t * 16;
    const bf16_t* g = bS + (size_t)h * 128 * K + j * 64;
    gload_lds16(g, d);
    gload_lds16(g + 32, d + 8192);
  };
  auto LA = [&](int c, int half, int mi, int kk) {
    return *(const bf16x8*)(sMem + c * 65536 + wm * 16384 + kk * 8192 +
                            (half * 64 + mi * 16 + lr) * 64 + colb);
  };
  auto LB = [&](int c, int ni, int kk) {
    return *(const bf16x8*)(sMem + c * 65536 + 32768 + (wn >> 1) * 16384 + kk * 8192 +
                            ((wn & 1) * 64 + ni * 16 + lr) * 64 + colb);
  };

  f32x4 acc[8][4];
#pragma unroll
  for (int i = 0; i < 8; ++i)
#pragma unroll
    for (int n = 0; n < 4; ++n) acc[i][n] = f32x4{0.f, 0.f, 0.f, 0.f};

  stA(0, 0, 0); stA(0, 1, 0); stB(0, 0, 0); stB(0, 1, 0);
  stB(1, 0, 1); stB(1, 1, 1);
  asm volatile("s_waitcnt vmcnt(4)" ::: "memory");
  __builtin_amdgcn_s_barrier();
  __builtin_amdgcn_sched_barrier(0);

  bf16x8 af[4][2], bf[2][2], bf2[2][2];
  for (int j = 0; j < 64; ++j) {
    const int c = j & 1, cn = c ^ 1;
    const int jp1 = (j + 1 < 64) ? j + 1 : 63;
    const int jp2 = (j + 2 < 64) ? j + 2 : 63;
    // ---- ph0: read A-half0 + B n0/1; stage A0(j+1); MFMA m0 x n0
#pragma unroll
    for (int mi = 0; mi < 4; ++mi)
#pragma unroll
      for (int kk = 0; kk < 2; ++kk) af[mi][kk] = LA(c, 0, mi, kk);
#pragma unroll
    for (int ni = 0; ni < 2; ++ni)
#pragma unroll
      for (int kk = 0; kk < 2; ++kk) bf[ni][kk] = LB(c, ni, kk);
    stA(cn, 0, jp1);
    __builtin_amdgcn_s_barrier();
    __builtin_amdgcn_sched_barrier(0);
    __builtin_amdgcn_s_setprio(1);
#pragma unroll
    for (int kk = 0; kk < 2; ++kk)
#pragma unroll
      for (int mi = 0; mi < 4; ++mi)
#pragma unroll
        for (int ni = 0; ni < 2; ++ni)
          acc[mi][ni] = __builtin_amdgcn_mfma_f32_16x16x32_bf16(af[mi][kk], bf[ni][kk],
                                                                acc[mi][ni], 0, 0, 0);
    __builtin_amdgcn_s_setprio(0);
    __builtin_amdgcn_sched_barrier(0);
    __builtin_amdgcn_s_barrier();
    // ---- ph1: read B n2/3; stage A1(j+1); MFMA m0 x n1
#pragma unroll
    for (int ni = 0; ni < 2; ++ni)
#pragma unroll
      for (int kk = 0; kk < 2; ++kk) bf2[ni][kk] = LB(c, 2 + ni, kk);
    stA(cn, 1, jp1);
    __builtin_amdgcn_s_barrier();
    __builtin_amdgcn_sched_barrier(0);
    __builtin_amdgcn_s_setprio(1);
#pragma unroll
    for (int kk = 0; kk < 2; ++kk)
#pragma unroll
      for (int mi = 0; mi < 4; ++mi)
#pragma unroll
        for (int ni = 0; ni < 2; ++ni)
          acc[mi][2 + ni] = __builtin_amdgcn_mfma_f32_16x16x32_bf16(af[mi][kk], bf2[ni][kk],
                                                                    acc[mi][2 + ni], 0, 0, 0);
    __builtin_amdgcn_s_setprio(0);
    __builtin_amdgcn_sched_barrier(0);
    __builtin_amdgcn_s_barrier();
    // ---- ph2: read A-half1; stage B0(j+2); MFMA m1 x n1
#pragma unroll
    for (int mi = 0; mi < 4; ++mi)
#pragma unroll
      for (int kk = 0; kk < 2; ++kk) af[mi][kk] = LA(c, 1, mi, kk);
    stB(c, 0, jp2);
    __builtin_amdgcn_s_barrier();
    __builtin_amdgcn_sched_barrier(0);
    __builtin_amdgcn_s_setprio(1);
#pragma unroll
    for (int kk = 0; kk < 2; ++kk)
#pragma unroll
      for (int mi = 0; mi < 4; ++mi)
#pragma unroll
        for (int ni = 0; ni < 2; ++ni)
          acc[4 + mi][2 + ni] = __builtin_amdgcn_mfma_f32_16x16x32_bf16(
              af[mi][kk], bf2[ni][kk], acc[4 + mi][2 + ni], 0, 0, 0);
    __builtin_amdgcn_s_setprio(0);
    __builtin_amdgcn_sched_barrier(0);
    __builtin_amdgcn_s_barrier();
    // ---- ph3: stage B1(j+2); MFMA m1 x n0 (reg operands); LATE vmcnt; 1 barrier
    stB(c, 1, jp2);
    __builtin_amdgcn_sched_barrier(0);
    __builtin_amdgcn_s_setprio(1);
#pragma unroll
    for (int kk = 0; kk < 2; ++kk)
#pragma unroll
      for (int mi = 0; mi < 4; ++mi)
#pragma unroll
        for (int ni = 0; ni < 2; ++ni)
          acc[4 + mi][ni] = __builtin_amdgcn_mfma_f32_16x16x32_bf16(
              af[mi][kk], bf[ni][kk], acc[4 + mi][ni], 0, 0, 0);
    __builtin_amdgcn_s_setprio(0);
    asm volatile("s_waitcnt vmcnt(4)" ::: "memory");
    __builtin_amdgcn_sched_barrier(0);
    __builtin_amdgcn_s_barrier();
  }

  if (nt < 20) {
    const bool isQ = nt < 16;
    bf16_t* dst = isQ ? Qb : Kb;
    const int ld = isQ ? 4096 : 1024;
    const int hh = isQ ? (nt * 2 + (wn >> 1)) : ((nt - 16) * 2 + (wn >> 1));
    // Q: 1/sqrt(128) * log2(e) folded (softmax uses exp2); K: unscaled
    const float qs = isQ ? 0.12751743f : 1.0f;
    const int dbase = lr + 32 * (wn & 1);
#pragma unroll
    for (int half = 0; half < 2; ++half)
#pragma unroll
      for (int mi = 0; mi < 4; ++mi)
#pragma unroll
        for (int ni = 0; ni < 2; ++ni) {
          int d = dbase + 16 * ni;
#pragma unroll
          for (int r = 0; r < 4; ++r) {
            int srow = bm + wm * 128 + half * 64 + mi * 16 + lq * 4 + r;
            float cv = cosT[srow * 64 + d], sv = sinT[srow * 64 + d];
            float x1 = acc[half * 4 + mi][ni][r], x2 = acc[half * 4 + mi][ni + 2][r];
            dst[(size_t)srow * ld + hh * 128 + d] = (bf16_t)((x1 * cv - x2 * sv) * qs);
            dst[(size_t)srow * ld + hh * 128 + d + 64] = (bf16_t)((x2 * cv + x1 * sv) * qs);
          }
        }
  } else {
    const int col0 = (nt - 20) * 256 + wn * 64;
#pragma unroll
    for (int half = 0; half < 2; ++half)
#pragma unroll
      for (int mi = 0; mi < 4; ++mi)
#pragma unroll
        for (int ni = 0; ni < 4; ++ni)
#pragma unroll
          for (int r = 0; r < 4; ++r) {
            int srow = bm + wm * 128 + half * 64 + mi * 16 + lq * 4 + r;
            Vb[(size_t)srow * 1024 + col0 + ni * 16 + lr] =
                (bf16_t)acc[half * 4 + mi][ni][r];
          }
  }
}

// ---------------------------------------------------------------------------
// Out-projection GEMM v2 (R11 — best measured): 256x128 tile, 8 waves,
// proj-style 4-phase schedule, grid 256 blocks (perfect CU fill).
// NEW: XCD-chunked block swizzle (256%8==0 -> bijective); 4 B-panels/XCD.
__global__ __launch_bounds__(512, 2) void out_gemm_kernel(
    const bf16_t* __restrict__ A, const bf16_t* __restrict__ B0,
    float* __restrict__ Cout) {
  constexpr int K = 4096;
  extern __shared__ unsigned char sMem[];
  const int bx = blockIdx.x;
  const int swzb = (bx & 7) * 32 + (bx >> 3);
  const int mt = swzb & 7, nt = swzb >> 3;  // 8 x 32
  const int bm = mt * 256;
  const bf16_t* Bt = B0 + (size_t)nt * 128 * K;

  const int t = threadIdx.x;  // 0..511
  const int rowU = t >> 2;
  const int cole = ((t & 3) * 8) ^ ((rowU & 8) ? 16 : 0);
  const bf16_t* aS = A + (size_t)(bm + rowU) * K + cole;
  const bf16_t* bS = Bt + (size_t)rowU * K + cole;

  const int lane = t & 63, w = t >> 6;
  const int wm = w >> 2, wn = w & 3;
  const int lr = lane & 15, lq = lane >> 4;
  const int colb = (lq * 16) ^ ((lr & 8) ? 32 : 0);

  auto stA = [&](int c, int h, int j) {
    unsigned char* d = sMem + c * 49152 + h * 16384 + t * 16;
    const bf16_t* g = aS + (size_t)h * 128 * K + j * 64;
    gload_lds16(g, d);
    gload_lds16(g + 32, d + 8192);
  };
  auto stB = [&](int c, int j) {
    unsigned char* d = sMem + c * 49152 + 32768 + t * 16;
    const bf16_t* g = bS + j * 64;
    gload_lds16(g, d);
    gload_lds16(g + 32, d + 8192);
  };
  auto LA = [&](int c, int half, int mi, int kk) {
    return *(const bf16x8*)(sMem + c * 49152 + wm * 16384 + kk * 8192 +
                            (half * 64 + mi * 16 + lr) * 64 + colb);
  };
  auto LB = [&](int c, int ni, int kk) {
    return *(const bf16x8*)(sMem + c * 49152 + 32768 + kk * 8192 +
                            (wn * 32 + ni * 16 + lr) * 64 + colb);
  };

  f32x4 acc[8][2];
#pragma unroll
  for (int i = 0; i < 8; ++i)
#pragma unroll
    for (int n = 0; n < 2; ++n) acc[i][n] = f32x4{0.f, 0.f, 0.f, 0.f};

  // prologue: tile0 fully + B(1); leave B(1) in flight
  stA(0, 0, 0); stA(0, 1, 0); stB(0, 0);
  stB(1, 1);
  asm volatile("s_waitcnt vmcnt(2)" ::: "memory");
  __builtin_amdgcn_s_barrier();
  __builtin_amdgcn_sched_barrier(0);

  bf16x8 af[4][2], bf0[2], bf1[2];
  for (int j = 0; j < 64; ++j) {
    const int c = j & 1, cn = c ^ 1;
    const int jp1 = (j + 1 < 64) ? j + 1 : 63;
    const int jp2 = (j + 2 < 64) ? j + 2 : 63;
    // ---- ph0: read A-half0 + B n0; stage A0(j+1); MFMA m0 x n0
#pragma unroll
    for (int mi = 0; mi < 4; ++mi)
#pragma unroll
      for (int kk = 0; kk < 2; ++kk) af[mi][kk] = LA(c, 0, mi, kk);
#pragma unroll
    for (int kk = 0; kk < 2; ++kk) bf0[kk] = LB(c, 0, kk);
    stA(cn, 0, jp1);
    __builtin_amdgcn_s_barrier();
    __builtin_amdgcn_sched_barrier(0);
    __builtin_amdgcn_s_setprio(1);
#pragma unroll
    for (int kk = 0; kk < 2; ++kk)
#pragma unroll
      for (int mi = 0; mi < 4; ++mi)
        acc[mi][0] = __builtin_amdgcn_mfma_f32_16x16x32_bf16(af[mi][kk], bf0[kk],
                                                             acc[mi][0], 0, 0, 0);
    __builtin_amdgcn_s_setprio(0);
    __builtin_amdgcn_sched_barrier(0);
    __builtin_amdgcn_s_barrier();
    // ---- ph1: read B n1; stage A1(j+1); MFMA m0 x n1
#pragma unroll
    for (int kk = 0; kk < 2; ++kk) bf1[kk] = LB(c, 1, kk);
    stA(cn, 1, jp1);
    __builtin_amdgcn_s_barrier();
    __builtin_amdgcn_sched_barrier(0);
    __builtin_amdgcn_s_setprio(1);
#pragma unroll
    for (int kk = 0; kk < 2; ++kk)
#pragma unroll
      for (int mi = 0; mi < 4; ++mi)
        acc[mi][1] = __builtin_amdgcn_mfma_f32_16x16x32_bf16(af[mi][kk], bf1[kk],
                                                             acc[mi][1], 0, 0, 0);
    __builtin_amdgcn_s_setprio(0);
    __builtin_amdgcn_sched_barrier(0);
    __builtin_amdgcn_s_barrier();
    // ---- ph2: read A-half1; stage B(j+2) into buf c (B(c) dead after ph1)
#pragma unroll
    for (int mi = 0; mi < 4; ++mi)
#pragma unroll
      for (int kk = 0; kk < 2; ++kk) af[mi][kk] = LA(c, 1, mi, kk);
    stB(c, jp2);
    __builtin_amdgcn_s_barrier();
    __builtin_amdgcn_sched_barrier(0);
    __builtin_amdgcn_s_setprio(1);
#pragma unroll
    for (int kk = 0; kk < 2; ++kk)
#pragma unroll
      for (int mi = 0; mi < 4; ++mi)
        acc[4 + mi][1] = __builtin_amdgcn_mfma_f32_16x16x32_bf16(af[mi][kk], bf1[kk],
                                                                 acc[4 + mi][1], 0, 0, 0);
    __builtin_amdgcn_s_setprio(0);
    __builtin_amdgcn_sched_barrier(0);
    __builtin_amdgcn_s_barrier();
    // ---- ph3: MFMA m1 x n0 (reg operands); vmcnt(2) -> A(j+1),B(j+1) landed
    __builtin_amdgcn_s_setprio(1);
#pragma unroll
    for (int kk = 0; kk < 2; ++kk)
#pragma unroll
      for (int mi = 0; mi < 4; ++mi)
        acc[4 + mi][0] = __builtin_amdgcn_mfma_f32_16x16x32_bf16(af[mi][kk], bf0[kk],
                                                                 acc[4 + mi][0], 0, 0, 0);
    __builtin_amdgcn_s_setprio(0);
    asm volatile("s_waitcnt vmcnt(2)" ::: "memory");
    __builtin_amdgcn_sched_barrier(0);
    __builtin_amdgcn_s_barrier();
  }

  // epilogue: row = bm + wm*128 + half*64 + mi*16 + lq*4 + r,
  //           col = nt*128 + wn*32 + ni*16 + lr
#pragma unroll
  for (int half = 0; half < 2; ++half)
#pragma unroll
    for (int mi = 0; mi < 4; ++mi)
#pragma unroll
      for (int ni = 0; ni < 2; ++ni)
#pragma unroll
        for (int r = 0; r < 4; ++r) {
          int row = bm + wm * 128 + half * 64 + mi * 16 + lq * 4 + r;
          Cout[(size_t)row * 4096 + nt * 128 + wn * 32 + ni * 16 + lr] =
              acc[half * 4 + mi][ni][r];
        }
}

// ---------------------------------------------------------------------------
// Flash attention v5 (R11): 8 waves x 32 q-rows, swapped-operand 32x32x16,
// exp2-domain softmax, P in registers, mask in LDS, counted vmcnt(4) loop.
__global__ __launch_bounds__(512) void attn_kernel(
    const bf16_t* __restrict__ Qb, const bf16_t* __restrict__ Kb,
    const bf16_t* __restrict__ Vt, const float* __restrict__ mask,
    bf16_t* __restrict__ Ob) {
  extern __shared__ unsigned char sMem[];
  const int bx = blockIdx.x;
  const int h = bx >> 3, qt = bx & 7;
  const int kvh = h >> 2;
  const int t = threadIdx.x, lane = t & 63, w = t >> 6;
  const int ln = lane & 31, hi = lane >> 5;
  const int q0 = qt * 256 + w * 32;
  const int swz = (ln & 7) << 4;

  bf16x8 qf[8];
#pragma unroll
  for (int ds = 0; ds < 8; ++ds)
    qf[ds] = *(const bf16x8*)(Qb + (size_t)(q0 + ln) * 4096 + h * 128 + ds * 16 + hi * 8);

  const int krow = t >> 4, kg = t & 15;
  const bf16_t* kSrc = Kb + (size_t)krow * 1024 + kvh * 128 +
                       (((kg * 16) ^ ((krow & 7) << 4)) >> 1);
  const int vrow = t >> 3, vg = t & 7;
  const bf16_t* vSrc = Vt + (size_t)(kvh * 128 + vrow) * 2048 +
                       (((vg * 16) ^ ((vrow & 7) << 4)) >> 1);

  auto stage = [&](int c, int kt) {  // uniform 4 loads per thread
    unsigned char* kD = sMem + c * 16384 + t * 16;
    unsigned char* vD = sMem + 32768 + c * 16384 + t * 16;
    gload_lds16(kSrc + (size_t)kt * 64 * 1024, kD);
    gload_lds16(kSrc + (size_t)(kt * 64 + 32) * 1024, kD + 8192);
    gload_lds16(vSrc + kt * 64, vD);
    gload_lds16(vSrc + (size_t)64 * 2048 + kt * 64, vD + 8192);
  };

  f32x16 o[4];
#pragma unroll
  for (int db = 0; db < 4; ++db)
#pragma unroll
    for (int e = 0; e < 16; ++e) o[db][e] = 0.f;
  float mrun = -1e30f, lp = 0.f;

  stage(0, 0);
  gload_lds16(mask + t * 4, sMem + 65536 + t * 16);
  asm volatile("s_waitcnt vmcnt(0)" ::: "memory");
  __builtin_amdgcn_s_barrier();
  __builtin_amdgcn_sched_barrier(0);

  for (int kt = 0; kt < 32; ++kt) {
    const int c = kt & 1;
    if (kt < 31) {
      stage(c ^ 1, kt + 1);
      asm volatile("s_waitcnt vmcnt(4)" ::: "memory");
    } else {
      asm volatile("s_waitcnt vmcnt(0)" ::: "memory");
    }
    __builtin_amdgcn_s_barrier();
    __builtin_amdgcn_sched_barrier(0);

    const unsigned char* sK = sMem + c * 16384;
    const unsigned char* sV = sMem + 32768 + c * 16384;
    const unsigned char* sMk = sMem + 65536 + kt * 256;

#pragma unroll
    for (int sub = 0; sub < 2; ++sub) {
      f32x16 s;
#pragma unroll
      for (int e = 0; e < 16; ++e) s[e] = 0.f;
      __builtin_amdgcn_s_setprio(1);
#pragma unroll
      for (int ds = 0; ds < 8; ++ds) {
        bf16x8 kf = *(const bf16x8*)(sK + (sub * 32 + ln) * 256 +
                                     ((ds * 32 + hi * 16) ^ swz));
        s = __builtin_amdgcn_mfma_f32_32x32x16_bf16(kf, qf[ds], s, 0, 0, 0);
      }
      __builtin_amdgcn_s_setprio(0);
#pragma unroll
      for (int rg = 0; rg < 4; ++rg) {
        float4 mv = *(const float4*)(sMk + (sub * 32 + rg * 8 + 4 * hi) * 4);
        s[rg * 4 + 0] += LOG2E * mv.x; s[rg * 4 + 1] += LOG2E * mv.y;
        s[rg * 4 + 2] += LOG2E * mv.z; s[rg * 4 + 3] += LOG2E * mv.w;
      }
      float pm = s[0];
#pragma unroll
      for (int e = 1; e < 16; ++e) pm = fmaxf(pm, s[e]);
      pm = fmaxf(pm, __shfl_xor(pm, 32));
      if (!__all(pm - mrun <= 11.5f)) {
        float nm = fmaxf(mrun, pm);
        float al = exp2f(mrun - nm);
        mrun = nm;
        lp *= al;
#pragma unroll
        for (int db = 0; db < 4; ++db)
#pragma unroll
          for (int e = 0; e < 16; ++e) o[db][e] *= al;
      }
      float p[16], ps = 0.f;
#pragma unroll
      for (int e = 0; e < 16; ++e) {
        p[e] = exp2f(s[e] - mrun);
        ps += p[e];
      }
      lp += ps;
#pragma unroll
      for (int hh = 0; hh < 2; ++hh) {
        unsigned w0 = pk_bf16(p[8 * hh + 0], p[8 * hh + 1]);
        unsigned w1 = pk_bf16(p[8 * hh + 2], p[8 * hh + 3]);
        unsigned w2 = pk_bf16(p[8 * hh + 4], p[8 * hh + 5]);
        unsigned w3 = pk_bf16(p[8 * hh + 6], p[8 * hh + 7]);
        unsigned pw0 = __shfl_xor((int)w0, 32), pw1 = __shfl_xor((int)w1, 32);
        unsigned pw2 = __shfl_xor((int)w2, 32), pw3 = __shfl_xor((int)w3, 32);
        union { unsigned u[4]; bf16x8 v; } pf;
        pf.u[0] = hi ? pw2 : w0;
        pf.u[1] = hi ? pw3 : w1;
        pf.u[2] = hi ? w2 : pw0;
        pf.u[3] = hi ? w3 : pw1;
        __builtin_amdgcn_s_setprio(1);
#pragma unroll
        for (int db = 0; db < 4; ++db) {
          bf16x8 vf = *(const bf16x8*)(sV + (db * 32 + ln) * 128 +
                                       ((sub * 64 + hh * 32 + hi * 16) ^ swz));
          o[db] = __builtin_amdgcn_mfma_f32_32x32x16_bf16(vf, pf.v, o[db], 0, 0, 0);
        }
        __builtin_amdgcn_s_setprio(0);
      }
    }
    __builtin_amdgcn_s_barrier();
    __builtin_amdgcn_sched_barrier(0);
  }

  float l = lp + __shfl_xor(lp, 32);
  float inv = 1.0f / l;
  bf16_t* orow = Ob + (size_t)(q0 + ln) * 4096 + h * 128;
#pragma unroll
  for (int db = 0; db < 4; ++db)
#pragma unroll
    for (int rg = 0; rg < 4; ++rg) {
      bf16x4 ov;
#pragma unroll
      for (int j = 0; j < 4; ++j) ov[j] = (bf16_t)(o[db][rg * 4 + j] * inv);
      *(bf16x4*)(orow + db * 32 + rg * 8 + hi * 4) = ov;
    }
}

// ---------------------------------------------------------------------------
extern "C" void kernel_launch(void* const* d_in, const int* in_sizes, int n_in,
                              void* d_out, int out_size, void* d_ws, size_t ws_size,
                              hipStream_t stream) {
  const float* hidden = (const float*)d_in[0];
  const float* mask = (const float*)d_in[1];
  const float* Wq = (const float*)d_in[2];
  const float* Wk = (const float*)d_in[3];
  const float* Wv = (const float*)d_in[4];
  const float* Wo = (const float*)d_in[5];
  float* out = (float*)d_out;
  char* ws = (char*)d_ws;

  bf16_t* hB   = (bf16_t*)(ws + 0);          //  16 MB  hidden bf16 [2048][4096]
  bf16_t* Wqt  = (bf16_t*)(ws + 16777216);   //  32 MB  Wq^T perm [4096][4096]
  bf16_t* Wkvt = (bf16_t*)(ws + 50331648);   //  16 MB  Wk^T perm | Wv^T [2048][4096]
  bf16_t* Wot  = (bf16_t*)(ws + 67108864);   //  32 MB  Wo^T  [4096][4096]
  bf16_t* Qb   = (bf16_t*)(ws + 100663296);  //  16 MB  Q roped+scaled [2048][4096]
  bf16_t* Kb   = (bf16_t*)(ws + 117440512);  //   4 MB  K roped [2048][1024]
  bf16_t* Vb   = (bf16_t*)(ws + 121634816);  //   4 MB  V [2048][1024]
  bf16_t* Vt   = (bf16_t*)(ws + 125829120);  //   4 MB  V^T [1024][2048]
  bf16_t* Ob   = (bf16_t*)(ws + 130023424);  //  16 MB  attn out [2048][4096]
  float*  cosT = (float*)(ws + 146800640);   // 0.5 MB
  float*  sinT = (float*)(ws + 147324928);   // 0.5 MB

  hipFuncSetAttribute((const void*)attn_kernel,
                      hipFuncAttributeMaxDynamicSharedMemorySize, 73728);
  hipFuncSetAttribute((const void*)proj_gemm_kernel,
                      hipFuncAttributeMaxDynamicSharedMemorySize, 131072);
  hipFuncSetAttribute((const void*)out_gemm_kernel,
                      hipFuncAttributeMaxDynamicSharedMemorySize, 98304);

  prep_kernel<<<29184, 256, 0, stream>>>(hidden, Wq, Wk, Wv, hB, Wqt, Wkvt,
                                         cosT, sinT);
  proj_gemm_kernel<<<256, 512, 131072, stream>>>(hB, Wqt, Wkvt, cosT, sinT,
                                                 Qb, Kb, Vb, Wo, Wot);
  trb_kernel<<<dim3(32, 64), dim3(32, 8), 0, stream>>>(Vb, Vt, 2048, 1024);
  attn_kernel<<<256, 512, 73728, stream>>>(Qb, Kb, Vt, mask, Ob);
  out_gemm_kernel<<<256, 512, 98304, stream>>>(Ob, Wot, out);
}

// Round 14
// 310.228 us; speedup vs baseline: 1.0230x; 1.0013x over previous
//
#include <hip/hip_runtime.h>
#include <hip/hip_bf16.h>

typedef __bf16 bf16_t;
typedef __bf16 bf16x8 __attribute__((ext_vector_type(8)));
typedef __bf16 bf16x4 __attribute__((ext_vector_type(4)));
typedef float f32x4 __attribute__((ext_vector_type(4)));
typedef float f32x16 __attribute__((ext_vector_type(16)));

#define LOG2E 1.4426950408889634f

// ---------------------------------------------------------------------------
// async global->LDS, 16B per lane (dest must be wave-uniform base + lane*16)
__device__ __forceinline__ void gload_lds16(const void* g, void* l) {
  __builtin_amdgcn_global_load_lds((const __attribute__((address_space(1))) void*)g,
                                   (__attribute__((address_space(3))) void*)l, 16, 0, 0);
}

// pack two f32 -> one u32 holding 2 bf16 (lo = a, hi = b)
__device__ __forceinline__ unsigned pk_bf16(float a, float b) {
  unsigned r;
  asm("v_cvt_pk_bf16_f32 %0, %1, %2" : "=v"(r) : "v"(a), "v"(b));
  return r;
}

// ---------------------------------------------------------------------------
// Fused prep kernel (Wot handled by proj helper blocks): 256-thread blocks.
__device__ __forceinline__ void trcvt_body(const float* src, bf16_t* dst, int R,
                                           int C, int cx, int cy, int tx, int ty,
                                           float (*tile)[33], bool perm) {
  int c0 = cx * 32, r0 = cy * 32;
#pragma unroll
  for (int i = 0; i < 4; ++i)
    tile[ty + i * 8][tx] = src[(size_t)(r0 + ty + i * 8) * C + c0 + tx];
  __syncthreads();
#pragma unroll
  for (int i = 0; i < 4; ++i) {
    int rc = c0 + ty + i * 8;
    int r_out = rc;
    if (perm) {
      int dd = rc & 127;
      int q = (dd & 15) + (dd & 16) + (((dd >> 5) & 1) ? 64 : 0) + ((dd >> 6) ? 32 : 0);
      r_out = (rc & ~127) | q;
    }
    dst[(size_t)r_out * R + r0 + tx] = (bf16_t)tile[tx][ty + i * 8];
  }
}

__global__ __launch_bounds__(256) void prep_kernel(
    const float* __restrict__ hidden, const float* __restrict__ Wq,
    const float* __restrict__ Wk, const float* __restrict__ Wv,
    bf16_t* __restrict__ hB, bf16_t* __restrict__ Wqt,
    bf16_t* __restrict__ Wkvt, float* __restrict__ cosT,
    float* __restrict__ sinT) {
  __shared__ float tile[32][33];
  const int bx = blockIdx.x;
  const int t = threadIdx.x;
  const int tx = t & 31, ty = t >> 5;
  if (bx < 4096) {
    int i = bx * 256 + t;
    const float4* s4 = (const float4*)hidden;
    float4 a = s4[2 * i], b = s4[2 * i + 1];
    bf16x8 o;
    o[0] = (bf16_t)a.x; o[1] = (bf16_t)a.y; o[2] = (bf16_t)a.z; o[3] = (bf16_t)a.w;
    o[4] = (bf16_t)b.x; o[5] = (bf16_t)b.y; o[6] = (bf16_t)b.z; o[7] = (bf16_t)b.w;
    *(bf16x8*)(hB + 8 * (size_t)i) = o;
  } else if (bx < 4608) {
    int i = (bx - 4096) * 256 + t;  // 2048*64
    int s = i >> 6, d = i & 63;
    float ang = (float)s * powf(10000.0f, -(float)d * (1.0f / 64.0f));
    cosT[i] = cosf(ang);
    sinT[i] = sinf(ang);
  } else if (bx < 20992) {
    int j = bx - 4608;
    trcvt_body(Wq, Wqt, 4096, 4096, j % 128, j / 128, tx, ty, tile, true);
  } else if (bx < 25088) {
    int j = bx - 20992;
    trcvt_body(Wk, Wkvt, 4096, 1024, j % 32, j / 32, tx, ty, tile, true);
  } else {
    int j = bx - 25088;
    trcvt_body(Wv, Wkvt + (size_t)1024 * 4096, 4096, 1024, j % 32, j / 32, tx, ty, tile, false);
  }
}

// bf16 [R][C] -> bf16 [C][R]  (V -> V^T for the attn PV A-operand)
__global__ __launch_bounds__(256) void trb_kernel(const bf16_t* __restrict__ src,
                                                  bf16_t* __restrict__ dst, int R, int C) {
  __shared__ bf16_t tile[32][33];
  int c0 = blockIdx.x * 32, r0 = blockIdx.y * 32;
  int tx = threadIdx.x, ty = threadIdx.y;
#pragma unroll
  for (int i = 0; i < 4; ++i)
    tile[ty + i * 8][tx] = src[(size_t)(r0 + ty + i * 8) * C + c0 + tx];
  __syncthreads();
#pragma unroll
  for (int i = 0; i < 4; ++i)
    dst[(size_t)(c0 + ty + i * 8) * R + r0 + tx] = tile[tx][ty + i * 8];
}

// ---------------------------------------------------------------------------
// Projection GEMM (R6/R11 schedule + R13 XCD swizzle — best measured):
// 256x256 tile, 8 waves, BK=64, 4 phases/K-tile, late vmcnt(4).
// Blocks 192..255: Wot transpose helpers (idle CUs; hidden).
__global__ __launch_bounds__(512, 2) void proj_gemm_kernel(
    const bf16_t* __restrict__ A, const bf16_t* __restrict__ Wqt,
    const bf16_t* __restrict__ Wkvt, const float* __restrict__ cosT,
    const float* __restrict__ sinT, bf16_t* __restrict__ Qb,
    bf16_t* __restrict__ Kb, bf16_t* __restrict__ Vb,
    const float* __restrict__ Wo, bf16_t* __restrict__ Wot) {
  constexpr int K = 4096;
  extern __shared__ unsigned char sMem[];
  const int bx = blockIdx.x;
  const int t = threadIdx.x;  // 0..511

  if (bx >= 192) {
    // ---- Wot helper: transpose+cvt a 64-column stripe of Wo (4096x4096 f32)
    float(*tl)[65] = (float(*)[65])sMem;
    const int c0 = (bx - 192) * 64;
    const int tc = t & 63, tr = t >> 6;  // 64 x 8
    for (int r0 = 0; r0 < 4096; r0 += 64) {
#pragma unroll
      for (int i = 0; i < 8; ++i)
        tl[tr + 8 * i][tc] = Wo[(size_t)(r0 + tr + 8 * i) * 4096 + c0 + tc];
      __syncthreads();
#pragma unroll
      for (int i = 0; i < 8; ++i)
        Wot[(size_t)(c0 + tr + 8 * i) * 4096 + r0 + tc] = (bf16_t)tl[tc][tr + 8 * i];
      __syncthreads();
    }
    return;
  }

  // XCD-chunked swizzle: XCD k (bx%8) gets logical tiles [k*24, (k+1)*24)
  const int swzb = (bx & 7) * 24 + (bx >> 3);
  const int mt = swzb & 7, nt = swzb >> 3;  // 8 x 24
  const int bm = mt * 256;
  const bf16_t* Btb = (nt < 16) ? (Wqt + (size_t)nt * 256 * K)
                                : (Wkvt + (size_t)(nt - 16) * 256 * K);

  const int rowU = t >> 2;
  const int cole = ((t & 3) * 8) ^ ((rowU & 8) ? 16 : 0);
  const bf16_t* aS = A + (size_t)(bm + rowU) * K + cole;
  const bf16_t* bS = Btb + (size_t)rowU * K + cole;

  const int lane = t & 63, w = t >> 6;
  const int wm = w >> 2, wn = w & 3;
  const int lr = lane & 15, lq = lane >> 4;
  const int colb = (lq * 16) ^ ((lr & 8) ? 32 : 0);

  auto stA = [&](int c, int h, int j) {
    unsigned char* d = sMem + c * 65536 + h * 16384 + t * 16;
    const bf16_t* g = aS + (size_t)h * 128 * K + j * 64;
    gload_lds16(g, d);
    gload_lds16(g + 32, d + 8192);
  };
  auto stB = [&](int c, int h, int j) {
    unsigned char* d = sMem + c * 65536 + 32768 + h * 16384 + t * 16;
    const bf16_t* g = bS + (size_t)h * 128 * K + j * 64;
    gload_lds16(g, d);
    gload_lds16(g + 32, d + 8192);
  };
  auto LA = [&](int c, int half, int mi, int kk) {
    return *(const bf16x8*)(sMem + c * 65536 + wm * 16384 + kk * 8192 +
                            (half * 64 + mi * 16 + lr) * 64 + colb);
  };
  auto LB = [&](int c, int ni, int kk) {
    return *(const bf16x8*)(sMem + c * 65536 + 32768 + (wn >> 1) * 16384 + kk * 8192 +
                            ((wn & 1) * 64 + ni * 16 + lr) * 64 + colb);
  };

  f32x4 acc[8][4];
#pragma unroll
  for (int i = 0; i < 8; ++i)
#pragma unroll
    for (int n = 0; n < 4; ++n) acc[i][n] = f32x4{0.f, 0.f, 0.f, 0.f};

  stA(0, 0, 0); stA(0, 1, 0); stB(0, 0, 0); stB(0, 1, 0);
  stB(1, 0, 1); stB(1, 1, 1);
  asm volatile("s_waitcnt vmcnt(4)" ::: "memory");
  __builtin_amdgcn_s_barrier();
  __builtin_amdgcn_sched_barrier(0);

  bf16x8 af[4][2], bf[2][2], bf2[2][2];
  for (int j = 0; j < 64; ++j) {
    const int c = j & 1, cn = c ^ 1;
    const int jp1 = (j + 1 < 64) ? j + 1 : 63;
    const int jp2 = (j + 2 < 64) ? j + 2 : 63;
    // ---- ph0: read A-half0 + B n0/1; stage A0(j+1); MFMA m0 x n0
#pragma unroll
    for (int mi = 0; mi < 4; ++mi)
#pragma unroll
      for (int kk = 0; kk < 2; ++kk) af[mi][kk] = LA(c, 0, mi, kk);
#pragma unroll
    for (int ni = 0; ni < 2; ++ni)
#pragma unroll
      for (int kk = 0; kk < 2; ++kk) bf[ni][kk] = LB(c, ni, kk);
    stA(cn, 0, jp1);
    __builtin_amdgcn_s_barrier();
    __builtin_amdgcn_sched_barrier(0);
    __builtin_amdgcn_s_setprio(1);
#pragma unroll
    for (int kk = 0; kk < 2; ++kk)
#pragma unroll
      for (int mi = 0; mi < 4; ++mi)
#pragma unroll
        for (int ni = 0; ni < 2; ++ni)
          acc[mi][ni] = __builtin_amdgcn_mfma_f32_16x16x32_bf16(af[mi][kk], bf[ni][kk],
                                                                acc[mi][ni], 0, 0, 0);
    __builtin_amdgcn_s_setprio(0);
    __builtin_amdgcn_sched_barrier(0);
    __builtin_amdgcn_s_barrier();
    // ---- ph1: read B n2/3; stage A1(j+1); MFMA m0 x n1
#pragma unroll
    for (int ni = 0; ni < 2; ++ni)
#pragma unroll
      for (int kk = 0; kk < 2; ++kk) bf2[ni][kk] = LB(c, 2 + ni, kk);
    stA(cn, 1, jp1);
    __builtin_amdgcn_s_barrier();
    __builtin_amdgcn_sched_barrier(0);
    __builtin_amdgcn_s_setprio(1);
#pragma unroll
    for (int kk = 0; kk < 2; ++kk)
#pragma unroll
      for (int mi = 0; mi < 4; ++mi)
#pragma unroll
        for (int ni = 0; ni < 2; ++ni)
          acc[mi][2 + ni] = __builtin_amdgcn_mfma_f32_16x16x32_bf16(af[mi][kk], bf2[ni][kk],
                                                                    acc[mi][2 + ni], 0, 0, 0);
    __builtin_amdgcn_s_setprio(0);
    __builtin_amdgcn_sched_barrier(0);
    __builtin_amdgcn_s_barrier();
    // ---- ph2: read A-half1; stage B0(j+2); MFMA m1 x n1
#pragma unroll
    for (int mi = 0; mi < 4; ++mi)
#pragma unroll
      for (int kk = 0; kk < 2; ++kk) af[mi][kk] = LA(c, 1, mi, kk);
    stB(c, 0, jp2);
    __builtin_amdgcn_s_barrier();
    __builtin_amdgcn_sched_barrier(0);
    __builtin_amdgcn_s_setprio(1);
#pragma unroll
    for (int kk = 0; kk < 2; ++kk)
#pragma unroll
      for (int mi = 0; mi < 4; ++mi)
#pragma unroll
        for (int ni = 0; ni < 2; ++ni)
          acc[4 + mi][2 + ni] = __builtin_amdgcn_mfma_f32_16x16x32_bf16(
              af[mi][kk], bf2[ni][kk], acc[4 + mi][2 + ni], 0, 0, 0);
    __builtin_amdgcn_s_setprio(0);
    __builtin_amdgcn_sched_barrier(0);
    __builtin_amdgcn_s_barrier();
    // ---- ph3: stage B1(j+2); MFMA m1 x n0 (reg operands); LATE vmcnt; 1 barrier
    stB(c, 1, jp2);
    __builtin_amdgcn_sched_barrier(0);
    __builtin_amdgcn_s_setprio(1);
#pragma unroll
    for (int kk = 0; kk < 2; ++kk)
#pragma unroll
      for (int mi = 0; mi < 4; ++mi)
#pragma unroll
        for (int ni = 0; ni < 2; ++ni)
          acc[4 + mi][ni] = __builtin_amdgcn_mfma_f32_16x16x32_bf16(
              af[mi][kk], bf[ni][kk], acc[4 + mi][ni], 0, 0, 0);
    __builtin_amdgcn_s_setprio(0);
    asm volatile("s_waitcnt vmcnt(4)" ::: "memory");
    __builtin_amdgcn_sched_barrier(0);
    __builtin_amdgcn_s_barrier();
  }

  if (nt < 20) {
    const bool isQ = nt < 16;
    bf16_t* dst = isQ ? Qb : Kb;
    const int ld = isQ ? 4096 : 1024;
    const int hh = isQ ? (nt * 2 + (wn >> 1)) : ((nt - 16) * 2 + (wn >> 1));
    // Q: 1/sqrt(128) * log2(e) folded (softmax uses exp2); K: unscaled
    const float qs = isQ ? 0.12751743f : 1.0f;
    const int dbase = lr + 32 * (wn & 1);
#pragma unroll
    for (int half = 0; half < 2; ++half)
#pragma unroll
      for (int mi = 0; mi < 4; ++mi)
#pragma unroll
        for (int ni = 0; ni < 2; ++ni) {
          int d = dbase + 16 * ni;
#pragma unroll
          for (int r = 0; r < 4; ++r) {
            int srow = bm + wm * 128 + half * 64 + mi * 16 + lq * 4 + r;
            float cv = cosT[srow * 64 + d], sv = sinT[srow * 64 + d];
            float x1 = acc[half * 4 + mi][ni][r], x2 = acc[half * 4 + mi][ni + 2][r];
            dst[(size_t)srow * ld + hh * 128 + d] = (bf16_t)((x1 * cv - x2 * sv) * qs);
            dst[(size_t)srow * ld + hh * 128 + d + 64] = (bf16_t)((x2 * cv + x1 * sv) * qs);
          }
        }
  } else {
    const int col0 = (nt - 20) * 256 + wn * 64;
#pragma unroll
    for (int half = 0; half < 2; ++half)
#pragma unroll
      for (int mi = 0; mi < 4; ++mi)
#pragma unroll
        for (int ni = 0; ni < 4; ++ni)
#pragma unroll
          for (int r = 0; r < 4; ++r) {
            int srow = bm + wm * 128 + half * 64 + mi * 16 + lq * 4 + r;
            Vb[(size_t)srow * 1024 + col0 + ni * 16 + lr] =
                (bf16_t)acc[half * 4 + mi][ni][r];
          }
  }
}

// ---------------------------------------------------------------------------
// Out-projection GEMM v2 (R11 + R13 XCD swizzle — best measured): 256x128
// tile, 8 waves, 4-phase schedule, grid 256 blocks, chunked swizzle.
__global__ __launch_bounds__(512, 2) void out_gemm_kernel(
    const bf16_t* __restrict__ A, const bf16_t* __restrict__ B0,
    float* __restrict__ Cout) {
  constexpr int K = 4096;
  extern __shared__ unsigned char sMem[];
  const int bx = blockIdx.x;
  const int swzb = (bx & 7) * 32 + (bx >> 3);
  const int mt = swzb & 7, nt = swzb >> 3;  // 8 x 32
  const int bm = mt * 256;
  const bf16_t* Bt = B0 + (size_t)nt * 128 * K;

  const int t = threadIdx.x;  // 0..511
  const int rowU = t >> 2;
  const int cole = ((t & 3) * 8) ^ ((rowU & 8) ? 16 : 0);
  const bf16_t* aS = A + (size_t)(bm + rowU) * K + cole;
  const bf16_t* bS = Bt + (size_t)rowU * K + cole;

  const int lane = t & 63, w = t >> 6;
  const int wm = w >> 2, wn = w & 3;
  const int lr = lane & 15, lq = lane >> 4;
  const int colb = (lq * 16) ^ ((lr & 8) ? 32 : 0);

  auto stA = [&](int c, int h, int j) {
    unsigned char* d = sMem + c * 49152 + h * 16384 + t * 16;
    const bf16_t* g = aS + (size_t)h * 128 * K + j * 64;
    gload_lds16(g, d);
    gload_lds16(g + 32, d + 8192);
  };
  auto stB = [&](int c, int j) {
    unsigned char* d = sMem + c * 49152 + 32768 + t * 16;
    const bf16_t* g = bS + j * 64;
    gload_lds16(g, d);
    gload_lds16(g + 32, d + 8192);
  };
  auto LA = [&](int c, int half, int mi, int kk) {
    return *(const bf16x8*)(sMem + c * 49152 + wm * 16384 + kk * 8192 +
                            (half * 64 + mi * 16 + lr) * 64 + colb);
  };
  auto LB = [&](int c, int ni, int kk) {
    return *(const bf16x8*)(sMem + c * 49152 + 32768 + kk * 8192 +
                            (wn * 32 + ni * 16 + lr) * 64 + colb);
  };

  f32x4 acc[8][2];
#pragma unroll
  for (int i = 0; i < 8; ++i)
#pragma unroll
    for (int n = 0; n < 2; ++n) acc[i][n] = f32x4{0.f, 0.f, 0.f, 0.f};

  // prologue: tile0 fully + B(1); leave B(1) in flight
  stA(0, 0, 0); stA(0, 1, 0); stB(0, 0);
  stB(1, 1);
  asm volatile("s_waitcnt vmcnt(2)" ::: "memory");
  __builtin_amdgcn_s_barrier();
  __builtin_amdgcn_sched_barrier(0);

  bf16x8 af[4][2], bf0[2], bf1[2];
  for (int j = 0; j < 64; ++j) {
    const int c = j & 1, cn = c ^ 1;
    const int jp1 = (j + 1 < 64) ? j + 1 : 63;
    const int jp2 = (j + 2 < 64) ? j + 2 : 63;
    // ---- ph0: read A-half0 + B n0; stage A0(j+1); MFMA m0 x n0
#pragma unroll
    for (int mi = 0; mi < 4; ++mi)
#pragma unroll
      for (int kk = 0; kk < 2; ++kk) af[mi][kk] = LA(c, 0, mi, kk);
#pragma unroll
    for (int kk = 0; kk < 2; ++kk) bf0[kk] = LB(c, 0, kk);
    stA(cn, 0, jp1);
    __builtin_amdgcn_s_barrier();
    __builtin_amdgcn_sched_barrier(0);
    __builtin_amdgcn_s_setprio(1);
#pragma unroll
    for (int kk = 0; kk < 2; ++kk)
#pragma unroll
      for (int mi = 0; mi < 4; ++mi)
        acc[mi][0] = __builtin_amdgcn_mfma_f32_16x16x32_bf16(af[mi][kk], bf0[kk],
                                                             acc[mi][0], 0, 0, 0);
    __builtin_amdgcn_s_setprio(0);
    __builtin_amdgcn_sched_barrier(0);
    __builtin_amdgcn_s_barrier();
    // ---- ph1: read B n1; stage A1(j+1); MFMA m0 x n1
#pragma unroll
    for (int kk = 0; kk < 2; ++kk) bf1[kk] = LB(c, 1, kk);
    stA(cn, 1, jp1);
    __builtin_amdgcn_s_barrier();
    __builtin_amdgcn_sched_barrier(0);
    __builtin_amdgcn_s_setprio(1);
#pragma unroll
    for (int kk = 0; kk < 2; ++kk)
#pragma unroll
      for (int mi = 0; mi < 4; ++mi)
        acc[mi][1] = __builtin_amdgcn_mfma_f32_16x16x32_bf16(af[mi][kk], bf1[kk],
                                                             acc[mi][1], 0, 0, 0);
    __builtin_amdgcn_s_setprio(0);
    __builtin_amdgcn_sched_barrier(0);
    __builtin_amdgcn_s_barrier();
    // ---- ph2: read A-half1; stage B(j+2) into buf c (B(c) dead after ph1)
#pragma unroll
    for (int mi = 0; mi < 4; ++mi)
#pragma unroll
      for (int kk = 0; kk < 2; ++kk) af[mi][kk] = LA(c, 1, mi, kk);
    stB(c, jp2);
    __builtin_amdgcn_s_barrier();
    __builtin_amdgcn_sched_barrier(0);
    __builtin_amdgcn_s_setprio(1);
#pragma unroll
    for (int kk = 0; kk < 2; ++kk)
#pragma unroll
      for (int mi = 0; mi < 4; ++mi)
        acc[4 + mi][1] = __builtin_amdgcn_mfma_f32_16x16x32_bf16(af[mi][kk], bf1[kk],
                                                                 acc[4 + mi][1], 0, 0, 0);
    __builtin_amdgcn_s_setprio(0);
    __builtin_amdgcn_sched_barrier(0);
    __builtin_amdgcn_s_barrier();
    // ---- ph3: MFMA m1 x n0 (reg operands); vmcnt(2) -> A(j+1),B(j+1) landed
    __builtin_amdgcn_s_setprio(1);
#pragma unroll
    for (int kk = 0; kk < 2; ++kk)
#pragma unroll
      for (int mi = 0; mi < 4; ++mi)
        acc[4 + mi][0] = __builtin_amdgcn_mfma_f32_16x16x32_bf16(af[mi][kk], bf0[kk],
                                                                 acc[4 + mi][0], 0, 0, 0);
    __builtin_amdgcn_s_setprio(0);
    asm volatile("s_waitcnt vmcnt(2)" ::: "memory");
    __builtin_amdgcn_sched_barrier(0);
    __builtin_amdgcn_s_barrier();
  }

  // epilogue
#pragma unroll
  for (int half = 0; half < 2; ++half)
#pragma unroll
    for (int mi = 0; mi < 4; ++mi)
#pragma unroll
      for (int ni = 0; ni < 2; ++ni)
#pragma unroll
        for (int r = 0; r < 4; ++r) {
          int row = bm + wm * 128 + half * 64 + mi * 16 + lq * 4 + r;
          Cout[(size_t)row * 4096 + nt * 128 + wn * 32 + ni * 16 + lr] =
              acc[half * 4 + mi][ni][r];
        }
}

// ---------------------------------------------------------------------------
// Flash attention v6: v5 + head-grouped XCD swizzle (XCD k owns kvh k ->
// its K/V working set = 1 MB, fully L2-resident instead of L3).
__global__ __launch_bounds__(512) void attn_kernel(
    const bf16_t* __restrict__ Qb, const bf16_t* __restrict__ Kb,
    const bf16_t* __restrict__ Vt, const float* __restrict__ mask,
    bf16_t* __restrict__ Ob) {
  extern __shared__ unsigned char sMem[];
  const int bx = blockIdx.x;
  const int swzb = (bx & 7) * 32 + (bx >> 3);  // bijective; XCD k -> heads 4k..4k+3
  const int h = swzb >> 3, qt = swzb & 7;
  const int kvh = h >> 2;
  const int t = threadIdx.x, lane = t & 63, w = t >> 6;
  const int ln = lane & 31, hi = lane >> 5;
  const int q0 = qt * 256 + w * 32;
  const int swz = (ln & 7) << 4;

  bf16x8 qf[8];
#pragma unroll
  for (int ds = 0; ds < 8; ++ds)
    qf[ds] = *(const bf16x8*)(Qb + (size_t)(q0 + ln) * 4096 + h * 128 + ds * 16 + hi * 8);

  const int krow = t >> 4, kg = t & 15;
  const bf16_t* kSrc = Kb + (size_t)krow * 1024 + kvh * 128 +
                       (((kg * 16) ^ ((krow & 7) << 4)) >> 1);
  const int vrow = t >> 3, vg = t & 7;
  const bf16_t* vSrc = Vt + (size_t)(kvh * 128 + vrow) * 2048 +
                       (((vg * 16) ^ ((vrow & 7) << 4)) >> 1);

  auto stage = [&](int c, int kt) {  // uniform 4 loads per thread
    unsigned char* kD = sMem + c * 16384 + t * 16;
    unsigned char* vD = sMem + 32768 + c * 16384 + t * 16;
    gload_lds16(kSrc + (size_t)kt * 64 * 1024, kD);
    gload_lds16(kSrc + (size_t)(kt * 64 + 32) * 1024, kD + 8192);
    gload_lds16(vSrc + kt * 64, vD);
    gload_lds16(vSrc + (size_t)64 * 2048 + kt * 64, vD + 8192);
  };

  f32x16 o[4];
#pragma unroll
  for (int db = 0; db < 4; ++db)
#pragma unroll
    for (int e = 0; e < 16; ++e) o[db][e] = 0.f;
  float mrun = -1e30f, lp = 0.f;

  stage(0, 0);
  gload_lds16(mask + t * 4, sMem + 65536 + t * 16);
  asm volatile("s_waitcnt vmcnt(0)" ::: "memory");
  __builtin_amdgcn_s_barrier();
  __builtin_amdgcn_sched_barrier(0);

  for (int kt = 0; kt < 32; ++kt) {
    const int c = kt & 1;
    if (kt < 31) {
      stage(c ^ 1, kt + 1);
      asm volatile("s_waitcnt vmcnt(4)" ::: "memory");
    } else {
      asm volatile("s_waitcnt vmcnt(0)" ::: "memory");
    }
    __builtin_amdgcn_s_barrier();
    __builtin_amdgcn_sched_barrier(0);

    const unsigned char* sK = sMem + c * 16384;
    const unsigned char* sV = sMem + 32768 + c * 16384;
    const unsigned char* sMk = sMem + 65536 + kt * 256;

#pragma unroll
    for (int sub = 0; sub < 2; ++sub) {
      f32x16 s;
#pragma unroll
      for (int e = 0; e < 16; ++e) s[e] = 0.f;
      __builtin_amdgcn_s_setprio(1);
#pragma unroll
      for (int ds = 0; ds < 8; ++ds) {
        bf16x8 kf = *(const bf16x8*)(sK + (sub * 32 + ln) * 256 +
                                     ((ds * 32 + hi * 16) ^ swz));
        s = __builtin_amdgcn_mfma_f32_32x32x16_bf16(kf, qf[ds], s, 0, 0, 0);
      }
      __builtin_amdgcn_s_setprio(0);
#pragma unroll
      for (int rg = 0; rg < 4; ++rg) {
        float4 mv = *(const float4*)(sMk + (sub * 32 + rg * 8 + 4 * hi) * 4);
        s[rg * 4 + 0] += LOG2E * mv.x; s[rg * 4 + 1] += LOG2E * mv.y;
        s[rg * 4 + 2] += LOG2E * mv.z; s[rg * 4 + 3] += LOG2E * mv.w;
      }
      float pm = s[0];
#pragma unroll
      for (int e = 1; e < 16; ++e) pm = fmaxf(pm, s[e]);
      pm = fmaxf(pm, __shfl_xor(pm, 32));
      if (!__all(pm - mrun <= 11.5f)) {
        float nm = fmaxf(mrun, pm);
        float al = exp2f(mrun - nm);
        mrun = nm;
        lp *= al;
#pragma unroll
        for (int db = 0; db < 4; ++db)
#pragma unroll
          for (int e = 0; e < 16; ++e) o[db][e] *= al;
      }
      float p[16], ps = 0.f;
#pragma unroll
      for (int e = 0; e < 16; ++e) {
        p[e] = exp2f(s[e] - mrun);
        ps += p[e];
      }
      lp += ps;
#pragma unroll
      for (int hh = 0; hh < 2; ++hh) {
        unsigned w0 = pk_bf16(p[8 * hh + 0], p[8 * hh + 1]);
        unsigned w1 = pk_bf16(p[8 * hh + 2], p[8 * hh + 3]);
        unsigned w2 = pk_bf16(p[8 * hh + 4], p[8 * hh + 5]);
        unsigned w3 = pk_bf16(p[8 * hh + 6], p[8 * hh + 7]);
        unsigned pw0 = __shfl_xor((int)w0, 32), pw1 = __shfl_xor((int)w1, 32);
        unsigned pw2 = __shfl_xor((int)w2, 32), pw3 = __shfl_xor((int)w3, 32);
        union { unsigned u[4]; bf16x8 v; } pf;
        pf.u[0] = hi ? pw2 : w0;
        pf.u[1] = hi ? pw3 : w1;
        pf.u[2] = hi ? w2 : pw0;
        pf.u[3] = hi ? w3 : pw1;
        __builtin_amdgcn_s_setprio(1);
#pragma unroll
        for (int db = 0; db < 4; ++db) {
          bf16x8 vf = *(const bf16x8*)(sV + (db * 32 + ln) * 128 +
                                       ((sub * 64 + hh * 32 + hi * 16) ^ swz));
          o[db] = __builtin_amdgcn_mfma_f32_32x32x16_bf16(vf, pf.v, o[db], 0, 0, 0);
        }
        __builtin_amdgcn_s_setprio(0);
      }
    }
    __builtin_amdgcn_s_barrier();
    __builtin_amdgcn_sched_barrier(0);
  }

  float l = lp + __shfl_xor(lp, 32);
  float inv = 1.0f / l;
  bf16_t* orow = Ob + (size_t)(q0 + ln) * 4096 + h * 128;
#pragma unroll
  for (int db = 0; db < 4; ++db)
#pragma unroll
    for (int rg = 0; rg < 4; ++rg) {
      bf16x4 ov;
#pragma unroll
      for (int j = 0; j < 4; ++j) ov[j] = (bf16_t)(o[db][rg * 4 + j] * inv);
      *(bf16x4*)(orow + db * 32 + rg * 8 + hi * 4) = ov;
    }
}

// ---------------------------------------------------------------------------
extern "C" void kernel_launch(void* const* d_in, const int* in_sizes, int n_in,
                              void* d_out, int out_size, void* d_ws, size_t ws_size,
                              hipStream_t stream) {
  const float* hidden = (const float*)d_in[0];
  const float* mask = (const float*)d_in[1];
  const float* Wq = (const float*)d_in[2];
  const float* Wk = (const float*)d_in[3];
  const float* Wv = (const float*)d_in[4];
  const float* Wo = (const float*)d_in[5];
  float* out = (float*)d_out;
  char* ws = (char*)d_ws;

  bf16_t* hB   = (bf16_t*)(ws + 0);          //  16 MB  hidden bf16 [2048][4096]
  bf16_t* Wqt  = (bf16_t*)(ws + 16777216);   //  32 MB  Wq^T perm [4096][4096]
  bf16_t* Wkvt = (bf16_t*)(ws + 50331648);   //  16 MB  Wk^T perm | Wv^T [2048][4096]
  bf16_t* Wot  = (bf16_t*)(ws + 67108864);   //  32 MB  Wo^T  [4096][4096]
  bf16_t* Qb   = (bf16_t*)(ws + 100663296);  //  16 MB  Q roped+scaled [2048][4096]
  bf16_t* Kb   = (bf16_t*)(ws + 117440512);  //   4 MB  K roped [2048][1024]
  bf16_t* Vb   = (bf16_t*)(ws + 121634816);  //   4 MB  V [2048][1024]
  bf16_t* Vt   = (bf16_t*)(ws + 125829120);  //   4 MB  V^T [1024][2048]
  bf16_t* Ob   = (bf16_t*)(ws + 130023424);  //  16 MB  attn out [2048][4096]
  float*  cosT = (float*)(ws + 146800640);   // 0.5 MB
  float*  sinT = (float*)(ws + 147324928);   // 0.5 MB

  hipFuncSetAttribute((const void*)attn_kernel,
                      hipFuncAttributeMaxDynamicSharedMemorySize, 73728);
  hipFuncSetAttribute((const void*)proj_gemm_kernel,
                      hipFuncAttributeMaxDynamicSharedMemorySize, 131072);
  hipFuncSetAttribute((const void*)out_gemm_kernel,
                      hipFuncAttributeMaxDynamicSharedMemorySize, 98304);

  prep_kernel<<<29184, 256, 0, stream>>>(hidden, Wq, Wk, Wv, hB, Wqt, Wkvt,
                                         cosT, sinT);
  proj_gemm_kernel<<<256, 512, 131072, stream>>>(hB, Wqt, Wkvt, cosT, sinT,
                                                 Qb, Kb, Vb, Wo, Wot);
  trb_kernel<<<dim3(32, 64), dim3(32, 8), 0, stream>>>(Vb, Vt, 2048, 1024);
  attn_kernel<<<256, 512, 73728, stream>>>(Qb, Kb, Vt, mask, Ob);
  out_gemm_kernel<<<256, 512, 98304, stream>>>(Ob, Wot, out);
}